// Round 6
// baseline (620.156 us; speedup 1.0000x reference)
//
#include <hip/hip_runtime.h>
#include <cstdint>

typedef __attribute__((ext_vector_type(8))) short short8;
typedef __attribute__((ext_vector_type(4))) float f32x4;

#define DEVINL static __device__ __forceinline__

DEVINL ushort f2b(float f) {
    uint32_t u = __builtin_bit_cast(uint32_t, f);
    u += 0x7FFFu + ((u >> 16) & 1u);
    return (ushort)(u >> 16);
}

typedef __attribute__((address_space(3))) uint32_t lds_u32;
typedef const __attribute__((address_space(1))) uint32_t glb_u32;

DEVINL void load_lds_16(const ushort* g, ushort* l) {
    __builtin_amdgcn_global_load_lds((glb_u32*)g, (lds_u32*)l, 16, 0, 0);
}

// ---------------------------------------------------------------------------
// gemm_k_dev: C[M,N] tile (64x64) = A @ BT^T (+bias, epilogues), LDS-staged.
// ---------------------------------------------------------------------------
constexpr int EPI_F32      = 0;
constexpr int EPI_MUL_BF16 = 2;  // outb = (acc+bias) * extra[row*N+col]
constexpr int EPI_SCALE_FB = 3;  // v = (acc+bias)*extra[row]; outf & outb

template<int K, int EPI>
DEVINL void gemm_k_dev(
    const ushort* __restrict__ A, const ushort* __restrict__ BT,
    const float* __restrict__ bias, int N,
    float* __restrict__ outf, ushort* __restrict__ outb, int obld, int oboff,
    const float* __restrict__ extra, int bx, int by,
    ushort* Asm, ushort* Bsm)
{
    const int wave = threadIdx.x >> 6;
    const int lane = threadIdx.x & 63;
    const int quad = lane >> 4, l16 = lane & 15;
    const int lr = lane >> 3, ls = lane & 7;
    const int m0 = bx * 64, n0 = by * 64;

    f32x4 zero = {0.f, 0.f, 0.f, 0.f};
    f32x4 acc[4] = {zero, zero, zero, zero};

    for (int k0 = 0; k0 < K; k0 += 64) {
        #pragma unroll
        for (int p = 0; p < 2; ++p) {
            const int r = wave * 16 + p * 8 + lr;
            load_lds_16(A + (size_t)(m0 + r) * K + k0 + ((ls ^ (r & 7)) * 8),
                        Asm + (size_t)(wave * 16 + p * 8) * 64);
            load_lds_16(BT + (size_t)(n0 + r) * K + k0 + ((ls ^ (r & 7)) * 8),
                        Bsm + (size_t)(wave * 16 + p * 8) * 64);
        }
        __syncthreads();
        #pragma unroll
        for (int ks = 0; ks < 2; ++ks) {
            const int sl = ((ks * 4 + quad) ^ (l16 & 7)) * 8;
            short8 af = *(const short8*)(Asm + (wave * 16 + l16) * 64 + sl);
            #pragma unroll
            for (int c = 0; c < 4; ++c) {
                short8 bf = *(const short8*)(Bsm + (c * 16 + l16) * 64 + sl);
                acc[c] = __builtin_amdgcn_mfma_f32_16x16x32_bf16(af, bf, acc[c], 0, 0, 0);
            }
        }
        __syncthreads();
    }

    #pragma unroll
    for (int r = 0; r < 4; ++r) {
        const int row = m0 + wave * 16 + quad * 4 + r;
        #pragma unroll
        for (int c = 0; c < 4; ++c) {
            const int col = n0 + c * 16 + l16;
            float v = acc[c][r] + (bias ? bias[col] : 0.f);
            if (EPI == EPI_MUL_BF16) v *= extra[(size_t)row * N + col];
            if (EPI == EPI_SCALE_FB) v *= extra[row];
            if (EPI == EPI_F32 || EPI == EPI_SCALE_FB)
                outf[(size_t)row * N + col] = v;
            if (EPI == EPI_MUL_BF16 || EPI == EPI_SCALE_FB)
                outb[(size_t)row * obld + oboff + col] = f2b(v);
        }
    }
}

// ---------------------------------------------------------------------------
// gemm_wh: Wh = hbf @ wT. Writes Wh f32, Whbf bf16, WhT bf16 (LDS transpose),
// and fused s/d row-dot atomics. BM=64, BN=64, K=256, grid (128,4).
// ---------------------------------------------------------------------------
__global__ __launch_bounds__(256) void gemm_wh_kernel(
    const ushort* __restrict__ A, const ushort* __restrict__ BT,
    const float* __restrict__ asrc, const float* __restrict__ adst,
    float* __restrict__ Wh, ushort* __restrict__ Whbf, ushort* __restrict__ WhT,
    float* __restrict__ sOut, float* __restrict__ dOut)
{
    __shared__ ushort smem[2 * 64 * 64];   // Asm | Bsm; reused as Tsm (64x72)
    ushort* Asm = smem;
    ushort* Bsm = smem + 4096;
    constexpr int K = 256;

    const int tid = threadIdx.x;
    const int wave = tid >> 6, lane = tid & 63;
    const int quad = lane >> 4, l16 = lane & 15;
    const int lr = lane >> 3, ls = lane & 7;
    const int m0 = blockIdx.x * 64, n0 = blockIdx.y * 64;

    f32x4 zero = {0.f, 0.f, 0.f, 0.f};
    f32x4 acc[4] = {zero, zero, zero, zero};

    for (int k0 = 0; k0 < K; k0 += 64) {
        #pragma unroll
        for (int p = 0; p < 2; ++p) {
            const int r = wave * 16 + p * 8 + lr;
            load_lds_16(A + (size_t)(m0 + r) * K + k0 + ((ls ^ (r & 7)) * 8),
                        Asm + (size_t)(wave * 16 + p * 8) * 64);
            load_lds_16(BT + (size_t)(n0 + r) * K + k0 + ((ls ^ (r & 7)) * 8),
                        Bsm + (size_t)(wave * 16 + p * 8) * 64);
        }
        __syncthreads();
        #pragma unroll
        for (int ks = 0; ks < 2; ++ks) {
            const int sl = ((ks * 4 + quad) ^ (l16 & 7)) * 8;
            short8 af = *(const short8*)(Asm + (wave * 16 + l16) * 64 + sl);
            #pragma unroll
            for (int c = 0; c < 4; ++c) {
                short8 bf = *(const short8*)(Bsm + (c * 16 + l16) * 64 + sl);
                acc[c] = __builtin_amdgcn_mfma_f32_16x16x32_bf16(af, bf, acc[c], 0, 0, 0);
            }
        }
        __syncthreads();
    }

    ushort* Tsm = smem;                     // 64 cols x 72 stride (9216 B)
    #pragma unroll
    for (int r = 0; r < 4; ++r) {
        const int rl = wave * 16 + quad * 4 + r;
        const int row = m0 + rl;
        float sp = 0.f, dp = 0.f;
        #pragma unroll
        for (int c = 0; c < 4; ++c) {
            const int cl = c * 16 + l16;
            const int col = n0 + cl;
            const float v = acc[c][r];
            Wh[(size_t)row * 256 + col] = v;
            const ushort b = f2b(v);
            Whbf[(size_t)row * 256 + col] = b;
            Tsm[cl * 72 + rl] = b;
            sp += v * asrc[col]; dp += v * adst[col];
        }
        #pragma unroll
        for (int o = 1; o < 16; o <<= 1) {
            sp += __shfl_xor(sp, o);
            dp += __shfl_xor(dp, o);
        }
        if (l16 == 0) {
            atomicAdd(&sOut[row], sp);
            atomicAdd(&dOut[row], dp);
        }
    }
    __syncthreads();
    // WhT[n0+cl][m0 .. +64): 4 threads per col, 16 ushorts each (coalesced)
    const int cl = tid >> 2, seg = tid & 3;
    const ushort* src = Tsm + cl * 72 + seg * 16;
    ushort* dst = WhT + (size_t)(n0 + cl) * 8192 + m0 + seg * 16;
    *(uint4*)(dst)     = *(const uint4*)(src);
    *(uint4*)(dst + 8) = *(const uint4*)(src + 8);
}

// ---------------------------------------------------------------------------
// gemm_row_dev: BM=16 rows, full N, fused row-local epilogues.
// ---------------------------------------------------------------------------
constexpr int EPR_LNSILU = 0;
constexpr int EPR_BCDT   = 1;
constexpr int EPR_HZ     = 2;
constexpr int EPR_FINAL  = 3;

template<int K, int N, int EPI>
DEVINL void gemm_row_dev(
    const ushort* __restrict__ A, const ushort* __restrict__ BT,
    const float* __restrict__ bias,
    float* __restrict__ outf, ushort* __restrict__ outb,
    const float* __restrict__ q0, const float* __restrict__ q1,
    const float* __restrict__ q2, const float* __restrict__ q3,
    const float* __restrict__ q4,
    int bx, int by, ushort* Asm, ushort* Bsm, float* red)
{
    constexpr int NW = N / 4;
    constexpr int NF = NW / 16;

    const int wave = threadIdx.x >> 6;
    const int lane = threadIdx.x & 63;
    const int quad = lane >> 4, l16 = lane & 15;
    const int lr = lane >> 3, ls = lane & 7;
    const int m0 = bx * 16;
    const ushort* Bb = BT + (EPI == EPR_HZ ? (size_t)by * 512 * K : 0);

    f32x4 zero = {0.f, 0.f, 0.f, 0.f};
    f32x4 acc[NF];
    #pragma unroll
    for (int c = 0; c < NF; ++c) acc[c] = zero;

    for (int k0 = 0; k0 < K; k0 += 64) {
        if (wave < 2) {
            const int r = wave * 8 + lr;
            load_lds_16(A + (size_t)(m0 + r) * K + k0 + ((ls ^ (r & 7)) * 8),
                        Asm + (size_t)(wave * 8) * 64);
        }
        #pragma unroll
        for (int p = 0; p < NW / 8; ++p) {
            const int n = wave * NW + p * 8 + lr;
            load_lds_16(Bb + (size_t)n * K + k0 + ((ls ^ (n & 7)) * 8),
                        Bsm + (size_t)(wave * NW + p * 8) * 64);
        }
        __syncthreads();
        #pragma unroll
        for (int ks = 0; ks < 2; ++ks) {
            const int sl = ((ks * 4 + quad) ^ (l16 & 7)) * 8;
            short8 af = *(const short8*)(Asm + l16 * 64 + sl);
            #pragma unroll
            for (int c = 0; c < NF; ++c) {
                const int gf = (EPI == EPR_BCDT) ? (wave + 4 * c) : (wave * NF + c);
                short8 bf = *(const short8*)(Bsm + (gf * 16 + l16) * 64 + sl);
                acc[c] = __builtin_amdgcn_mfma_f32_16x16x32_bf16(af, bf, acc[c], 0, 0, 0);
            }
        }
        __syncthreads();
    }

    if constexpr (EPI != EPR_HZ) {
        #pragma unroll
        for (int c = 0; c < NF; ++c) {
            const int gf = (EPI == EPR_BCDT) ? (wave + 4 * c) : (wave * NF + c);
            const float bs = bias[gf * 16 + l16];
            #pragma unroll
            for (int r = 0; r < 4; ++r) acc[c][r] += bs;
        }
    }

    if constexpr (EPI == EPR_LNSILU) {
        float s[4], q[4];
        #pragma unroll
        for (int r = 0; r < 4; ++r) {
            s[r] = 0.f; q[r] = 0.f;
            #pragma unroll
            for (int c = 0; c < NF; ++c) { const float v = acc[c][r]; s[r] += v; q[r] += v * v; }
            #pragma unroll
            for (int o = 1; o < 16; o <<= 1) { s[r] += __shfl_xor(s[r], o); q[r] += __shfl_xor(q[r], o); }
        }
        if (l16 == 0) {
            #pragma unroll
            for (int r = 0; r < 4; ++r) {
                red[(quad * 4 + r) * 8 + wave * 2]     = s[r];
                red[(quad * 4 + r) * 8 + wave * 2 + 1] = q[r];
            }
        }
        __syncthreads();
        #pragma unroll
        for (int r = 0; r < 4; ++r) {
            const int row16 = quad * 4 + r;
            float S = 0.f, Q = 0.f;
            #pragma unroll
            for (int w = 0; w < 4; ++w) { S += red[row16 * 8 + w * 2]; Q += red[row16 * 8 + w * 2 + 1]; }
            const float mean = S * (1.f / N);
            const float rstd = rsqrtf(Q * (1.f / N) - mean * mean + 1e-5f);
            #pragma unroll
            for (int c = 0; c < NF; ++c) {
                const int col = (wave * NF + c) * 16 + l16;
                const float y = (acc[c][r] - mean) * rstd * q0[col] + q1[col];
                outb[(size_t)(m0 + row16) * N + col] = f2b(y / (1.f + __expf(-y)));
            }
        }
    } else if constexpr (EPI == EPR_BCDT) {
        float t[2][4], e[2][4];
        #pragma unroll
        for (int ci = 0; ci < 2; ++ci) {
            const int dcol = (wave + 4 * (ci + 4)) * 16 - 256 + l16;
            const float av = q0[dcol];
            #pragma unroll
            for (int r = 0; r < 4; ++r) t[ci][r] = acc[ci + 4][r] + av;
        }
        float pm[4];
        #pragma unroll
        for (int r = 0; r < 4; ++r) {
            pm[r] = fmaxf(t[0][r], t[1][r]);
            #pragma unroll
            for (int o = 1; o < 16; o <<= 1) pm[r] = fmaxf(pm[r], __shfl_xor(pm[r], o));
        }
        if (l16 == 0) {
            #pragma unroll
            for (int r = 0; r < 4; ++r) red[(quad * 4 + r) * 4 + wave] = pm[r];
        }
        __syncthreads();
        float mx[4];
        #pragma unroll
        for (int r = 0; r < 4; ++r) {
            const int row16 = quad * 4 + r;
            mx[r] = fmaxf(fmaxf(red[row16 * 4], red[row16 * 4 + 1]),
                          fmaxf(red[row16 * 4 + 2], red[row16 * 4 + 3]));
        }
        float pe[4], pc[4];
        #pragma unroll
        for (int r = 0; r < 4; ++r) {
            e[0][r] = __expf(t[0][r] - mx[r]);
            e[1][r] = __expf(t[1][r] - mx[r]);
            pe[r] = e[0][r] + e[1][r];
            pc[r] = 0.f;
            #pragma unroll
            for (int ci = 0; ci < 2; ++ci) {
                const int ccol = (wave + 4 * (ci + 2)) * 16 - 128 + l16;
                pc[r] += acc[ci + 2][r] * q1[ccol];
            }
            #pragma unroll
            for (int o = 1; o < 16; o <<= 1) { pe[r] += __shfl_xor(pe[r], o); pc[r] += __shfl_xor(pc[r], o); }
        }
        if (l16 == 0) {
            #pragma unroll
            for (int r = 0; r < 4; ++r) {
                red[64  + (quad * 4 + r) * 4 + wave] = pe[r];
                red[128 + (quad * 4 + r) * 4 + wave] = pc[r];
            }
        }
        __syncthreads();
        #pragma unroll
        for (int r = 0; r < 4; ++r) {
            const int row16 = quad * 4 + r;
            const float inv = 1.f / (red[64 + row16 * 4] + red[64 + row16 * 4 + 1] +
                                     red[64 + row16 * 4 + 2] + red[64 + row16 * 4 + 3]);
            #pragma unroll
            for (int ci = 0; ci < 2; ++ci) {
                const int bcol = (wave + 4 * ci) * 16 + l16;
                outb[(size_t)(m0 + row16) * 128 + bcol] = f2b(acc[ci][r] * e[ci][r] * inv);
            }
        }
        if (wave == 0 && l16 == 0) {
            #pragma unroll
            for (int r = 0; r < 4; ++r) {
                const int row16 = quad * 4 + r;
                outf[m0 + row16] = 1.f + red[128 + row16 * 4] + red[128 + row16 * 4 + 1] +
                                   red[128 + row16 * 4 + 2] + red[128 + row16 * 4 + 3] + q2[0];
            }
        }
    } else if constexpr (EPI == EPR_HZ) {
        float* ep = (float*)Bsm;
        const float D0 = q0[0];
        if (wave >= 2) {
            #pragma unroll
            for (int c = 0; c < NF; ++c) {
                const int lc = (wave * NF + c) * 16 + l16;
                const float bz = bias[512 + by * 256 + lc - 256];
                #pragma unroll
                for (int r = 0; r < 4; ++r) {
                    const float z = acc[c][r] + bz;
                    ep[(quad * 4 + r) * 256 + lc - 256] = z / (1.f + __expf(-z)) + D0;
                }
            }
        }
        __syncthreads();
        if (wave < 2) {
            #pragma unroll
            for (int c = 0; c < NF; ++c) {
                const int lc = (wave * NF + c) * 16 + l16;
                const float bh = bias[by * 256 + lc];
                #pragma unroll
                for (int r = 0; r < 4; ++r) {
                    const float v = (acc[c][r] + bh) * ep[(quad * 4 + r) * 256 + lc];
                    outb[(size_t)(m0 + quad * 4 + r) * 512 + by * 256 + lc] = f2b(v);
                }
            }
        }
    } else {  // EPR_FINAL
        float fv[NF][4], s[4], q[4];
        #pragma unroll
        for (int r = 0; r < 4; ++r) { s[r] = 0.f; q[r] = 0.f; }
        #pragma unroll
        for (int c = 0; c < NF; ++c) {
            const int col = (wave * NF + c) * 16 + l16;
            #pragma unroll
            for (int r = 0; r < 4; ++r) {
                const size_t idx = (size_t)(m0 + quad * 4 + r) * 256 + col;
                const float g = 1.f / (1.f + __expf(-acc[c][r]));
                const float f = g * q0[idx] + (1.f - g) * q1[idx] + q2[idx];
                fv[c][r] = f; s[r] += f; q[r] += f * f;
            }
        }
        #pragma unroll
        for (int r = 0; r < 4; ++r) {
            #pragma unroll
            for (int o = 1; o < 16; o <<= 1) { s[r] += __shfl_xor(s[r], o); q[r] += __shfl_xor(q[r], o); }
        }
        if (l16 == 0) {
            #pragma unroll
            for (int r = 0; r < 4; ++r) {
                red[(quad * 4 + r) * 8 + wave * 2]     = s[r];
                red[(quad * 4 + r) * 8 + wave * 2 + 1] = q[r];
            }
        }
        __syncthreads();
        #pragma unroll
        for (int r = 0; r < 4; ++r) {
            const int row16 = quad * 4 + r;
            float S = 0.f, Q = 0.f;
            #pragma unroll
            for (int w = 0; w < 4; ++w) { S += red[row16 * 8 + w * 2]; Q += red[row16 * 8 + w * 2 + 1]; }
            const float mean = S * (1.f / 256.f);
            const float rstd = rsqrtf(Q * (1.f / 256.f) - mean * mean + 1e-5f);
            #pragma unroll
            for (int c = 0; c < NF; ++c) {
                const int col = (wave * NF + c) * 16 + l16;
                outf[(size_t)(m0 + row16) * 256 + col] = (fv[c][r] - mean) * rstd * q3[col] + q4[col];
            }
        }
    }
}

// ---------------------------------------------------------------------------
// Fused GAT attention v6: js=8 (grid 1024 = ~4 blocks/CU), adj register
// prefetch (next chunk's adj loads issue before current exp chain).
// ---------------------------------------------------------------------------
__global__ __launch_bounds__(256, 3) void attn_kernel(
    const int* __restrict__ adj, const float* __restrict__ sA,
    const float* __restrict__ dA, const ushort* __restrict__ WhT,
    float* __restrict__ Upart, float* __restrict__ lpart)
{
    __shared__ ushort vsm[256 * 64];
    __shared__ ushort wsm[64 * 64];

    const int tid  = threadIdx.x;
    const int wave = tid >> 6, lane = tid & 63, quad = lane >> 4, l16 = lane & 15;
    const int lr = lane >> 3, ls = lane & 7;
    const int i0 = blockIdx.x * 64;
    const int js = blockIdx.y;
    const int jbase = js * 1024;
    const int pr = tid >> 2, pc = tid & 3;
    const float s_r = sA[i0 + pr];
    const int* adjp = adj + (size_t)(i0 + pr) * 8192 + jbase;
    const int rt = wave & 1, ch = wave >> 1;

    f32x4 zero = {0.f, 0.f, 0.f, 0.f};
    f32x4 acc[2][8] = {{zero, zero, zero, zero, zero, zero, zero, zero},
                       {zero, zero, zero, zero, zero, zero, zero, zero}};
    float lsum = 0.f;

    int4 ca[2][2];
    #pragma unroll
    for (int gi = 0; gi < 2; ++gi) {
        const int g = pc + gi * 4;
        ca[gi][0] = *(const int4*)(adjp + g * 8);
        ca[gi][1] = *(const int4*)(adjp + g * 8 + 4);
    }

    for (int c64 = 0; c64 < 1024; c64 += 64) {
        #pragma unroll
        for (int p = 0; p < 8; ++p) {
            const int f = wave * 64 + p * 8 + lr;
            load_lds_16(WhT + (size_t)f * 8192 + jbase + c64 + ((ls ^ (f & 7)) * 8),
                        vsm + (size_t)(wave * 64 + p * 8) * 64);
        }
        const bool more = (c64 + 64 < 1024);
        int4 na[2][2];
        if (more) {
            #pragma unroll
            for (int gi = 0; gi < 2; ++gi) {
                const int g = pc + gi * 4;
                na[gi][0] = *(const int4*)(adjp + c64 + 64 + g * 8);
                na[gi][1] = *(const int4*)(adjp + c64 + 64 + g * 8 + 4);
            }
        }
        #pragma unroll
        for (int gi = 0; gi < 2; ++gi) {
            const int g = pc + gi * 4;
            const float4 d0 = *(const float4*)(dA + jbase + c64 + g * 8);
            const float4 d1 = *(const float4*)(dA + jbase + c64 + g * 8 + 4);
            const int   aa[8] = {ca[gi][0].x, ca[gi][0].y, ca[gi][0].z, ca[gi][0].w,
                                 ca[gi][1].x, ca[gi][1].y, ca[gi][1].z, ca[gi][1].w};
            const float dd[8] = {d0.x, d0.y, d0.z, d0.w, d1.x, d1.y, d1.z, d1.w};
            union { ushort us[8]; uint4 v; } pk;
            #pragma unroll
            for (int q = 0; q < 8; ++q) {
                float e = s_r + dd[q];
                e = fmaxf(e, 0.2f * e);
                const float w = aa[q] ? __expf(e) : 0.f;
                lsum += w; pk.us[q] = f2b(w);
            }
            *(uint4*)(wsm + pr * 64 + ((g ^ (pr & 7)) * 8)) = pk.v;
        }
        __syncthreads();

        #pragma unroll
        for (int ks = 0; ks < 2; ++ks) {
            const int sl = ((ks * 4 + quad) ^ (l16 & 7)) * 8;
            short8 a0 = *(const short8*)(wsm + (rt * 32 + l16) * 64 + sl);
            short8 a1 = *(const short8*)(wsm + (rt * 32 + 16 + l16) * 64 + sl);
            #pragma unroll
            for (int c = 0; c < 8; ++c) {
                short8 bf = *(const short8*)(vsm + (ch * 128 + c * 16 + l16) * 64 + sl);
                acc[0][c] = __builtin_amdgcn_mfma_f32_16x16x32_bf16(a0, bf, acc[0][c], 0, 0, 0);
                acc[1][c] = __builtin_amdgcn_mfma_f32_16x16x32_bf16(a1, bf, acc[1][c], 0, 0, 0);
            }
        }
        __syncthreads();
        if (more) {
            #pragma unroll
            for (int gi = 0; gi < 2; ++gi) {
                ca[gi][0] = na[gi][0];
                ca[gi][1] = na[gi][1];
            }
        }
    }

    lsum += __shfl_down(lsum, 1);
    lsum += __shfl_down(lsum, 2);
    if (pc == 0) lpart[(size_t)js * 8192 + i0 + pr] = lsum;

    #pragma unroll
    for (int it = 0; it < 2; ++it) {
        #pragma unroll
        for (int c = 0; c < 8; ++c) {
            const int col = ch * 128 + c * 16 + l16;
            #pragma unroll
            for (int r = 0; r < 4; ++r) {
                const int row = i0 + rt * 32 + it * 16 + quad * 4 + r;
                Upart[((size_t)js * 8192 + row) * 256 + col] = acc[it][c][r];
            }
        }
    }
}

// ---------------------------------------------------------------------------
// post_attn: blocks [0,2048) combine; [2048,2560) fe1+LN+silu; [2560,3072) bcdt
// ---------------------------------------------------------------------------
__global__ __launch_bounds__(256) void post_attn_kernel(
    const float* __restrict__ Upart, const float* __restrict__ lpart,
    float* __restrict__ hattn, ushort* __restrict__ comb,
    const ushort* __restrict__ Whbf,
    const ushort* __restrict__ fe1T, const float* __restrict__ fe1_b,
    const float* __restrict__ fe_ln_g, const float* __restrict__ fe_ln_b,
    ushort* __restrict__ tact,
    const ushort* __restrict__ bcdtT, const float* __restrict__ b_bcdt,
    const float* __restrict__ Avec, const float* __restrict__ cpw,
    const float* __restrict__ cpb,
    ushort* __restrict__ SB, float* __restrict__ cscl)
{
    __shared__ ushort Asm[16 * 64];
    __shared__ ushort Bsm[512 * 64];
    __shared__ float red[192];
    const int b = blockIdx.x;

    if (b < 2048) {
        const int row = b * 4 + (threadIdx.x >> 6);
        const int lane = threadIdx.x & 63;
        float l = 0.f;
        #pragma unroll
        for (int js = 0; js < 8; ++js) l += lpart[(size_t)js * 8192 + row];
        const float inv = 1.f / l;
        float4 u = {0.f, 0.f, 0.f, 0.f};
        #pragma unroll
        for (int js = 0; js < 8; ++js) {
            const float4 t = *(const float4*)&Upart[((size_t)js * 8192 + row) * 256 + lane * 4];
            u.x += t.x; u.y += t.y; u.z += t.z; u.w += t.w;
        }
        u.x *= inv; u.y *= inv; u.z *= inv; u.w *= inv;
        *(float4*)&hattn[(size_t)row * 256 + lane * 4] = u;
        union { ushort us[4]; uint2 v; } pk;
        pk.us[0] = f2b(u.x); pk.us[1] = f2b(u.y); pk.us[2] = f2b(u.z); pk.us[3] = f2b(u.w);
        *(uint2*)&comb[(size_t)row * 512 + lane * 4] = pk.v;
    } else if (b < 2560) {
        gemm_row_dev<256, 512, EPR_LNSILU>(Whbf, fe1T, fe1_b, nullptr, tact,
            fe_ln_g, fe_ln_b, nullptr, nullptr, nullptr, b - 2048, 0, Asm, Bsm, red);
    } else {
        gemm_row_dev<256, 384, EPR_BCDT>(Whbf, bcdtT, b_bcdt, cscl, SB,
            Avec, cpw, cpb, nullptr, nullptr, b - 2560, 0, Asm, Bsm, red);
    }
}

// fe2 (blocks [0,512)) + SB gemm (blocks [512,1024))
__global__ __launch_bounds__(256) void gemm_fe2_sb_kernel(
    const ushort* __restrict__ tact, const ushort* __restrict__ fe2T,
    const float* __restrict__ fe2_b, float* __restrict__ henh,
    const ushort* __restrict__ SB, const ushort* __restrict__ abpT,
    const float* __restrict__ abp_b, ushort* __restrict__ hsbf,
    const float* __restrict__ Wh)
{
    __shared__ ushort Asm[64 * 64];
    __shared__ ushort Bsm[64 * 64];
    const int b = blockIdx.x;
    if (b < 512)
        gemm_k_dev<512, EPI_F32>(tact, fe2T, fe2_b, 256, henh, nullptr, 0, 0,
                                 nullptr, b & 127, b >> 7, Asm, Bsm);
    else
        gemm_k_dev<128, EPI_MUL_BF16>(SB, abpT, abp_b, 256, nullptr, hsbf, 256, 0,
                                      Wh, (b - 512) & 127, (b - 512) >> 7, Asm, Bsm);
}

__global__ __launch_bounds__(256) void gemm_hz_kernel(
    const ushort* __restrict__ hsbf, const ushort* __restrict__ hzT,
    const float* __restrict__ b_hz, ushort* __restrict__ vbf,
    const float* __restrict__ Dvec)
{
    __shared__ ushort Asm[16 * 64];
    __shared__ ushort Bsm[512 * 64];
    __shared__ float red[192];
    gemm_row_dev<256, 512, EPR_HZ>(hsbf, hzT, b_hz, nullptr, vbf, Dvec,
        nullptr, nullptr, nullptr, nullptr, blockIdx.x, blockIdx.y, Asm, Bsm, red);
}

__global__ __launch_bounds__(256) void gemm_out_kernel(
    const ushort* __restrict__ vbf, const ushort* __restrict__ outT,
    const float* __restrict__ out_b, float* __restrict__ hs2,
    ushort* __restrict__ comb, const float* __restrict__ cscl)
{
    __shared__ ushort Asm[64 * 64];
    __shared__ ushort Bsm[64 * 64];
    gemm_k_dev<512, EPI_SCALE_FB>(vbf, outT, out_b, 256, hs2, comb, 512, 256,
                                  cscl, blockIdx.x, blockIdx.y, Asm, Bsm);
}

__global__ __launch_bounds__(256) void gemm_g1_kernel(
    const ushort* __restrict__ comb, const ushort* __restrict__ g1T,
    const float* __restrict__ g1_b, ushort* __restrict__ tact,
    const float* __restrict__ g_ln_g, const float* __restrict__ g_ln_b)
{
    __shared__ ushort Asm[16 * 64];
    __shared__ ushort Bsm[512 * 64];
    __shared__ float red[192];
    gemm_row_dev<512, 512, EPR_LNSILU>(comb, g1T, g1_b, nullptr, tact,
        g_ln_g, g_ln_b, nullptr, nullptr, nullptr, blockIdx.x, 0, Asm, Bsm, red);
}

__global__ __launch_bounds__(256) void gemm_final_kernel(
    const ushort* __restrict__ tact, const ushort* __restrict__ g2T,
    const float* __restrict__ g2_b, float* __restrict__ outp,
    const float* __restrict__ hattn, const float* __restrict__ hs2,
    const float* __restrict__ henh, const float* __restrict__ ln_g,
    const float* __restrict__ ln_b)
{
    __shared__ ushort Asm[16 * 64];
    __shared__ ushort Bsm[256 * 64];
    __shared__ float red[192];
    gemm_row_dev<512, 256, EPR_FINAL>(tact, g2T, g2_b, outp, nullptr,
        hattn, hs2, henh, ln_g, ln_b, blockIdx.x, 0, Asm, Bsm, red);
}

// ---------------------------------------------------------------------------
// Descriptor-driven transpose/cast mega-kernel (+ hz column permutation)
// ---------------------------------------------------------------------------
struct TJob { const float* in; ushort* out; int R, C, off, perm; };
struct TArgs { TJob j[10]; };

DEVINL int hzperm(int j) {
    return (j < 512) ? ((j >> 8) << 9) + (j & 255)
                     : (((j - 512) >> 8) << 9) + 256 + ((j - 512) & 255);
}

__global__ __launch_bounds__(256) void multi_transpose_kernel(TArgs a)
{
    __shared__ float tile[32][33];
    const int b = blockIdx.x;
    int ji = 0;
    #pragma unroll
    for (int k = 1; k < 10; ++k) if (b >= a.j[k].off) ji = k;
    const TJob J = a.j[ji];
    const int t = b - J.off;

    if (J.R == 0) {
        const int base = t * 1024 + threadIdx.x;
        #pragma unroll
        for (int k = 0; k < 4; ++k)
            J.out[base + k * 256] = f2b(J.in[base + k * 256]);
        return;
    }
    const int CB = J.C >> 5;
    const int bx = t % CB, by = t / CB;
    const int tx = threadIdx.x & 31, ty = threadIdx.x >> 5;
    const int c0 = bx * 32, r0 = by * 32;
    #pragma unroll
    for (int i = ty; i < 32; i += 8)
        tile[i][tx] = J.in[(size_t)(r0 + i) * J.C + (c0 + tx)];
    __syncthreads();
    #pragma unroll
    for (int i = ty; i < 32; i += 8) {
        int orow = c0 + i;
        if (J.perm) orow = hzperm(orow);
        J.out[(size_t)orow * J.R + (r0 + tx)] = f2b(tile[tx][i]);
    }
}

// ---------------------------------------------------------------------------
extern "C" void kernel_launch(void* const* d_in, const int* in_sizes, int n_in,
                              void* d_out, int out_size, void* d_ws, size_t ws_size,
                              hipStream_t stream)
{
    const float* h      = (const float*)d_in[0];
    const int*   adj    = (const int*)  d_in[1];
    const float* W      = (const float*)d_in[2];
    const float* a_src  = (const float*)d_in[3];
    const float* a_dst  = (const float*)d_in[4];
    const float* W_bcdt = (const float*)d_in[5];
    const float* b_bcdt = (const float*)d_in[6];
    const float* abp_w  = (const float*)d_in[7];
    const float* abp_b  = (const float*)d_in[8];
    const float* cp_w   = (const float*)d_in[9];
    const float* cp_b   = (const float*)d_in[10];
    const float* W_hz   = (const float*)d_in[11];
    const float* b_hz   = (const float*)d_in[12];
    const float* out_w  = (const float*)d_in[13];
    const float* out_b  = (const float*)d_in[14];
    const float* fe1_w  = (const float*)d_in[15];
    const float* fe1_b  = (const float*)d_in[16];
    const float* fe_ln_g= (const float*)d_in[17];
    const float* fe_ln_b= (const float*)d_in[18];
    const float* fe2_w  = (const float*)d_in[19];
    const float* fe2_b  = (const float*)d_in[20];
    const float* Avec   = (const float*)d_in[21];
    const float* Dvec   = (const float*)d_in[22];
    const float* g1_w   = (const float*)d_in[23];
    const float* g1_b   = (const float*)d_in[24];
    const float* g_ln_g = (const float*)d_in[25];
    const float* g_ln_b = (const float*)d_in[26];
    const float* g2_w   = (const float*)d_in[27];
    const float* g2_b   = (const float*)d_in[28];
    const float* ln_g   = (const float*)d_in[29];
    const float* ln_b   = (const float*)d_in[30];
    float* outp = (float*)d_out;

    char* p = (char*)d_ws;
    size_t off = 0;
    auto take = [&](size_t nbytes) -> void* {
        void* r = p + off;
        off += (nbytes + 255) & ~(size_t)255;
        return r;
    };
    ushort* wT    = (ushort*)take(256 * 256 * 2);
    ushort* fe1T  = (ushort*)take(512 * 256 * 2);
    ushort* fe2T  = (ushort*)take(256 * 512 * 2);
    ushort* bcdtT = (ushort*)take(384 * 256 * 2);
    ushort* hzT   = (ushort*)take(1024 * 256 * 2);
    ushort* outT  = (ushort*)take(256 * 512 * 2);
    ushort* g1T   = (ushort*)take(512 * 512 * 2);
    ushort* g2T   = (ushort*)take(256 * 512 * 2);
    ushort* abpT  = (ushort*)take(256 * 128 * 2);
    ushort* hbf   = (ushort*)take((size_t)8192 * 256 * 2);
    float*  Wh    = (float*) take((size_t)8192 * 256 * 4);
    ushort* Whbf  = (ushort*)take((size_t)8192 * 256 * 2);
    ushort* WhT   = (ushort*)take((size_t)8192 * 256 * 2);
    float*  sbuf  = (float*) take(8192 * 4);
    float*  dbuf  = (float*) take(8192 * 4);
    float*  cscl  = (float*) take(8192 * 4);
    float*  hattn = (float*) take((size_t)8192 * 256 * 4);
    float*  henh  = (float*) take((size_t)8192 * 256 * 4);
    float*  lpart = (float*) take(8 * 8192 * 4);
    ushort* SB    = (ushort*)take((size_t)8192 * 128 * 2);
    ushort* hsbf  = (ushort*)take((size_t)8192 * 256 * 2);
    ushort* vbf   = (ushort*)take((size_t)8192 * 512 * 2);
    float*  hs2   = (float*) take((size_t)8192 * 256 * 4);
    ushort* comb  = (ushort*)take((size_t)8192 * 512 * 2);
    ushort* tact  = (ushort*)take((size_t)8192 * 512 * 2);
    float*  Upart = (float*) take((size_t)8 * 8192 * 256 * 4);

    (void)in_sizes; (void)n_in; (void)out_size; (void)ws_size;

    // zero s/d atomic accumulators (sbuf,dbuf contiguous)
    hipMemsetAsync(sbuf, 0, 2 * 8192 * sizeof(float), stream);

    // 1) all weight transposes + h cast
    {
        TArgs ta; int boff = 0;
        auto addT = [&](int i, const float* in, ushort* out, int R, int C, int perm) {
            ta.j[i] = TJob{in, out, R, C, boff, perm};
            boff += (R / 32) * (C / 32);
        };
        addT(0, W,      wT,    256, 256,  0);
        addT(1, fe1_w,  fe1T,  256, 512,  0);
        addT(2, fe2_w,  fe2T,  512, 256,  0);
        addT(3, W_bcdt, bcdtT, 256, 384,  0);
        addT(4, abp_w,  abpT,  128, 256,  0);
        addT(5, W_hz,   hzT,   256, 1024, 1);
        addT(6, out_w,  outT,  512, 256,  0);
        addT(7, g1_w,   g1T,   512, 512,  0);
        addT(8, g2_w,   g2T,   512, 256,  0);
        ta.j[9] = TJob{h, hbf, 0, 8192 * 256, boff, 0};
        boff += (8192 * 256) / 1024;
        multi_transpose_kernel<<<boff, 256, 0, stream>>>(ta);
    }

    // 2) Wh gemm (Wh f32 + Whbf + WhT + s/d dots)
    gemm_wh_kernel<<<dim3(128, 4), 256, 0, stream>>>(
        hbf, wT, a_src, a_dst, Wh, Whbf, WhT, sbuf, dbuf);

    // 3) attention (8-way j-split, adj prefetch)
    attn_kernel<<<dim3(128, 8), 256, 0, stream>>>(adj, sbuf, dbuf, WhT, Upart, lpart);

    // 4) combine + fe1(+LN+silu) + bcdt(+softmax+cscale)
    post_attn_kernel<<<3072, 256, 0, stream>>>(
        Upart, lpart, hattn, comb, Whbf,
        fe1T, fe1_b, fe_ln_g, fe_ln_b, tact,
        bcdtT, b_bcdt, Avec, cp_w, cp_b, SB, cscl);

    // 5) fe2 + SB gemm
    gemm_fe2_sb_kernel<<<1024, 256, 0, stream>>>(
        tact, fe2T, fe2_b, henh, SB, abpT, abp_b, hsbf, Wh);

    // 6) hz (+ h*(silu(z)+D))
    gemm_hz_kernel<<<dim3(512, 2), 256, 0, stream>>>(hsbf, hzT, b_hz, vbf, Dvec);

    // 7) out gemm (*cscale)
    gemm_out_kernel<<<dim3(128, 4), 256, 0, stream>>>(vbf, outT, out_b, hs2, comb, cscl);

    // 8) g1 (+LN+silu)
    gemm_g1_kernel<<<512, 256, 0, stream>>>(comb, g1T, g1_b, tact, g_ln_g, g_ln_b);

    // 9) g2 + sigmoid + gated fuse + final LN
    gemm_final_kernel<<<512, 256, 0, stream>>>(
        tact, g2T, g2_b, outp, hattn, hs2, henh, ln_g, ln_b);
}

// Round 7
// 608.876 us; speedup vs baseline: 1.0185x; 1.0185x over previous
//
#include <hip/hip_runtime.h>
#include <cstdint>

typedef __attribute__((ext_vector_type(8))) short short8;
typedef __attribute__((ext_vector_type(4))) float f32x4;

#define DEVINL static __device__ __forceinline__

DEVINL ushort f2b(float f) {
    uint32_t u = __builtin_bit_cast(uint32_t, f);
    u += 0x7FFFu + ((u >> 16) & 1u);
    return (ushort)(u >> 16);
}

typedef __attribute__((address_space(3))) uint32_t lds_u32;
typedef const __attribute__((address_space(1))) uint32_t glb_u32;

DEVINL void load_lds_16(const ushort* g, ushort* l) {
    __builtin_amdgcn_global_load_lds((glb_u32*)g, (lds_u32*)l, 16, 0, 0);
}

// Raw barriers with manual waitcnt (AITER pattern): vmcnt(16) keeps the 16
// newest vm ops (8 DMA + 8 prefetch of the NEXT chunk) in flight across the
// barrier; everything older (this chunk's DMA, issued one iter ago) is drained.
DEVINL void barrier_vm16() { asm volatile("s_waitcnt vmcnt(16) lgkmcnt(0)\ns_barrier" ::: "memory"); }
DEVINL void barrier_lgkm() { asm volatile("s_waitcnt lgkmcnt(0)\ns_barrier" ::: "memory"); }

// ---------------------------------------------------------------------------
// gemm_k_dev: C[M,N] tile (64x64) = A @ BT^T (+bias, epilogues), LDS-staged.
// ---------------------------------------------------------------------------
constexpr int EPI_F32      = 0;
constexpr int EPI_MUL_BF16 = 2;
constexpr int EPI_SCALE_FB = 3;

template<int K, int EPI>
DEVINL void gemm_k_dev(
    const ushort* __restrict__ A, const ushort* __restrict__ BT,
    const float* __restrict__ bias, int N,
    float* __restrict__ outf, ushort* __restrict__ outb, int obld, int oboff,
    const float* __restrict__ extra, int bx, int by,
    ushort* Asm, ushort* Bsm)
{
    const int wave = threadIdx.x >> 6;
    const int lane = threadIdx.x & 63;
    const int quad = lane >> 4, l16 = lane & 15;
    const int lr = lane >> 3, ls = lane & 7;
    const int m0 = bx * 64, n0 = by * 64;

    f32x4 zero = {0.f, 0.f, 0.f, 0.f};
    f32x4 acc[4] = {zero, zero, zero, zero};

    for (int k0 = 0; k0 < K; k0 += 64) {
        #pragma unroll
        for (int p = 0; p < 2; ++p) {
            const int r = wave * 16 + p * 8 + lr;
            load_lds_16(A + (size_t)(m0 + r) * K + k0 + ((ls ^ (r & 7)) * 8),
                        Asm + (size_t)(wave * 16 + p * 8) * 64);
            load_lds_16(BT + (size_t)(n0 + r) * K + k0 + ((ls ^ (r & 7)) * 8),
                        Bsm + (size_t)(wave * 16 + p * 8) * 64);
        }
        __syncthreads();
        #pragma unroll
        for (int ks = 0; ks < 2; ++ks) {
            const int sl = ((ks * 4 + quad) ^ (l16 & 7)) * 8;
            short8 af = *(const short8*)(Asm + (wave * 16 + l16) * 64 + sl);
            #pragma unroll
            for (int c = 0; c < 4; ++c) {
                short8 bf = *(const short8*)(Bsm + (c * 16 + l16) * 64 + sl);
                acc[c] = __builtin_amdgcn_mfma_f32_16x16x32_bf16(af, bf, acc[c], 0, 0, 0);
            }
        }
        __syncthreads();
    }

    #pragma unroll
    for (int r = 0; r < 4; ++r) {
        const int row = m0 + wave * 16 + quad * 4 + r;
        #pragma unroll
        for (int c = 0; c < 4; ++c) {
            const int col = n0 + c * 16 + l16;
            float v = acc[c][r] + (bias ? bias[col] : 0.f);
            if (EPI == EPI_MUL_BF16) v *= extra[(size_t)row * N + col];
            if (EPI == EPI_SCALE_FB) v *= extra[row];
            if (EPI == EPI_F32 || EPI == EPI_SCALE_FB)
                outf[(size_t)row * N + col] = v;
            if (EPI == EPI_MUL_BF16 || EPI == EPI_SCALE_FB)
                outb[(size_t)row * obld + oboff + col] = f2b(v);
        }
    }
}

// ---------------------------------------------------------------------------
// gemm_wh: Wh = hbf @ wT. Writes Wh f32, Whbf, WhT (LDS transpose), s/d dots.
// ---------------------------------------------------------------------------
__global__ __launch_bounds__(256) void gemm_wh_kernel(
    const ushort* __restrict__ A, const ushort* __restrict__ BT,
    const float* __restrict__ asrc, const float* __restrict__ adst,
    float* __restrict__ Wh, ushort* __restrict__ Whbf, ushort* __restrict__ WhT,
    float* __restrict__ sOut, float* __restrict__ dOut)
{
    __shared__ ushort smem[2 * 64 * 64];
    ushort* Asm = smem;
    ushort* Bsm = smem + 4096;
    constexpr int K = 256;

    const int tid = threadIdx.x;
    const int wave = tid >> 6, lane = tid & 63;
    const int quad = lane >> 4, l16 = lane & 15;
    const int lr = lane >> 3, ls = lane & 7;
    const int m0 = blockIdx.x * 64, n0 = blockIdx.y * 64;

    f32x4 zero = {0.f, 0.f, 0.f, 0.f};
    f32x4 acc[4] = {zero, zero, zero, zero};

    for (int k0 = 0; k0 < K; k0 += 64) {
        #pragma unroll
        for (int p = 0; p < 2; ++p) {
            const int r = wave * 16 + p * 8 + lr;
            load_lds_16(A + (size_t)(m0 + r) * K + k0 + ((ls ^ (r & 7)) * 8),
                        Asm + (size_t)(wave * 16 + p * 8) * 64);
            load_lds_16(BT + (size_t)(n0 + r) * K + k0 + ((ls ^ (r & 7)) * 8),
                        Bsm + (size_t)(wave * 16 + p * 8) * 64);
        }
        __syncthreads();
        #pragma unroll
        for (int ks = 0; ks < 2; ++ks) {
            const int sl = ((ks * 4 + quad) ^ (l16 & 7)) * 8;
            short8 af = *(const short8*)(Asm + (wave * 16 + l16) * 64 + sl);
            #pragma unroll
            for (int c = 0; c < 4; ++c) {
                short8 bf = *(const short8*)(Bsm + (c * 16 + l16) * 64 + sl);
                acc[c] = __builtin_amdgcn_mfma_f32_16x16x32_bf16(af, bf, acc[c], 0, 0, 0);
            }
        }
        __syncthreads();
    }

    ushort* Tsm = smem;
    #pragma unroll
    for (int r = 0; r < 4; ++r) {
        const int rl = wave * 16 + quad * 4 + r;
        const int row = m0 + rl;
        float sp = 0.f, dp = 0.f;
        #pragma unroll
        for (int c = 0; c < 4; ++c) {
            const int cl = c * 16 + l16;
            const int col = n0 + cl;
            const float v = acc[c][r];
            Wh[(size_t)row * 256 + col] = v;
            const ushort b = f2b(v);
            Whbf[(size_t)row * 256 + col] = b;
            Tsm[cl * 72 + rl] = b;
            sp += v * asrc[col]; dp += v * adst[col];
        }
        #pragma unroll
        for (int o = 1; o < 16; o <<= 1) {
            sp += __shfl_xor(sp, o);
            dp += __shfl_xor(dp, o);
        }
        if (l16 == 0) {
            atomicAdd(&sOut[row], sp);
            atomicAdd(&dOut[row], dp);
        }
    }
    __syncthreads();
    const int cl = tid >> 2, seg = tid & 3;
    const ushort* src = Tsm + cl * 72 + seg * 16;
    ushort* dst = WhT + (size_t)(n0 + cl) * 8192 + m0 + seg * 16;
    *(uint4*)(dst)     = *(const uint4*)(src);
    *(uint4*)(dst + 8) = *(const uint4*)(src + 8);
}

// ---------------------------------------------------------------------------
// gemm_row_dev: BM=16 rows, full N, fused row-local epilogues.
// ---------------------------------------------------------------------------
constexpr int EPR_LNSILU = 0;
constexpr int EPR_BCDT   = 1;
constexpr int EPR_HZ     = 2;
constexpr int EPR_FINAL  = 3;

template<int K, int N, int EPI>
DEVINL void gemm_row_dev(
    const ushort* __restrict__ A, const ushort* __restrict__ BT,
    const float* __restrict__ bias,
    float* __restrict__ outf, ushort* __restrict__ outb,
    const float* __restrict__ q0, const float* __restrict__ q1,
    const float* __restrict__ q2, const float* __restrict__ q3,
    const float* __restrict__ q4,
    int bx, int by, ushort* Asm, ushort* Bsm, float* red)
{
    constexpr int NW = N / 4;
    constexpr int NF = NW / 16;

    const int wave = threadIdx.x >> 6;
    const int lane = threadIdx.x & 63;
    const int quad = lane >> 4, l16 = lane & 15;
    const int lr = lane >> 3, ls = lane & 7;
    const int m0 = bx * 16;
    const ushort* Bb = BT + (EPI == EPR_HZ ? (size_t)by * 512 * K : 0);

    f32x4 zero = {0.f, 0.f, 0.f, 0.f};
    f32x4 acc[NF];
    #pragma unroll
    for (int c = 0; c < NF; ++c) acc[c] = zero;

    for (int k0 = 0; k0 < K; k0 += 64) {
        if (wave < 2) {
            const int r = wave * 8 + lr;
            load_lds_16(A + (size_t)(m0 + r) * K + k0 + ((ls ^ (r & 7)) * 8),
                        Asm + (size_t)(wave * 8) * 64);
        }
        #pragma unroll
        for (int p = 0; p < NW / 8; ++p) {
            const int n = wave * NW + p * 8 + lr;
            load_lds_16(Bb + (size_t)n * K + k0 + ((ls ^ (n & 7)) * 8),
                        Bsm + (size_t)(wave * NW + p * 8) * 64);
        }
        __syncthreads();
        #pragma unroll
        for (int ks = 0; ks < 2; ++ks) {
            const int sl = ((ks * 4 + quad) ^ (l16 & 7)) * 8;
            short8 af = *(const short8*)(Asm + l16 * 64 + sl);
            #pragma unroll
            for (int c = 0; c < NF; ++c) {
                const int gf = (EPI == EPR_BCDT) ? (wave + 4 * c) : (wave * NF + c);
                short8 bf = *(const short8*)(Bsm + (gf * 16 + l16) * 64 + sl);
                acc[c] = __builtin_amdgcn_mfma_f32_16x16x32_bf16(af, bf, acc[c], 0, 0, 0);
            }
        }
        __syncthreads();
    }

    if constexpr (EPI != EPR_HZ) {
        #pragma unroll
        for (int c = 0; c < NF; ++c) {
            const int gf = (EPI == EPR_BCDT) ? (wave + 4 * c) : (wave * NF + c);
            const float bs = bias[gf * 16 + l16];
            #pragma unroll
            for (int r = 0; r < 4; ++r) acc[c][r] += bs;
        }
    }

    if constexpr (EPI == EPR_LNSILU) {
        float s[4], q[4];
        #pragma unroll
        for (int r = 0; r < 4; ++r) {
            s[r] = 0.f; q[r] = 0.f;
            #pragma unroll
            for (int c = 0; c < NF; ++c) { const float v = acc[c][r]; s[r] += v; q[r] += v * v; }
            #pragma unroll
            for (int o = 1; o < 16; o <<= 1) { s[r] += __shfl_xor(s[r], o); q[r] += __shfl_xor(q[r], o); }
        }
        if (l16 == 0) {
            #pragma unroll
            for (int r = 0; r < 4; ++r) {
                red[(quad * 4 + r) * 8 + wave * 2]     = s[r];
                red[(quad * 4 + r) * 8 + wave * 2 + 1] = q[r];
            }
        }
        __syncthreads();
        #pragma unroll
        for (int r = 0; r < 4; ++r) {
            const int row16 = quad * 4 + r;
            float S = 0.f, Q = 0.f;
            #pragma unroll
            for (int w = 0; w < 4; ++w) { S += red[row16 * 8 + w * 2]; Q += red[row16 * 8 + w * 2 + 1]; }
            const float mean = S * (1.f / N);
            const float rstd = rsqrtf(Q * (1.f / N) - mean * mean + 1e-5f);
            #pragma unroll
            for (int c = 0; c < NF; ++c) {
                const int col = (wave * NF + c) * 16 + l16;
                const float y = (acc[c][r] - mean) * rstd * q0[col] + q1[col];
                outb[(size_t)(m0 + row16) * N + col] = f2b(y / (1.f + __expf(-y)));
            }
        }
    } else if constexpr (EPI == EPR_BCDT) {
        float t[2][4], e[2][4];
        #pragma unroll
        for (int ci = 0; ci < 2; ++ci) {
            const int dcol = (wave + 4 * (ci + 4)) * 16 - 256 + l16;
            const float av = q0[dcol];
            #pragma unroll
            for (int r = 0; r < 4; ++r) t[ci][r] = acc[ci + 4][r] + av;
        }
        float pm[4];
        #pragma unroll
        for (int r = 0; r < 4; ++r) {
            pm[r] = fmaxf(t[0][r], t[1][r]);
            #pragma unroll
            for (int o = 1; o < 16; o <<= 1) pm[r] = fmaxf(pm[r], __shfl_xor(pm[r], o));
        }
        if (l16 == 0) {
            #pragma unroll
            for (int r = 0; r < 4; ++r) red[(quad * 4 + r) * 4 + wave] = pm[r];
        }
        __syncthreads();
        float mx[4];
        #pragma unroll
        for (int r = 0; r < 4; ++r) {
            const int row16 = quad * 4 + r;
            mx[r] = fmaxf(fmaxf(red[row16 * 4], red[row16 * 4 + 1]),
                          fmaxf(red[row16 * 4 + 2], red[row16 * 4 + 3]));
        }
        float pe[4], pc2[4];
        #pragma unroll
        for (int r = 0; r < 4; ++r) {
            e[0][r] = __expf(t[0][r] - mx[r]);
            e[1][r] = __expf(t[1][r] - mx[r]);
            pe[r] = e[0][r] + e[1][r];
            pc2[r] = 0.f;
            #pragma unroll
            for (int ci = 0; ci < 2; ++ci) {
                const int ccol = (wave + 4 * (ci + 2)) * 16 - 128 + l16;
                pc2[r] += acc[ci + 2][r] * q1[ccol];
            }
            #pragma unroll
            for (int o = 1; o < 16; o <<= 1) { pe[r] += __shfl_xor(pe[r], o); pc2[r] += __shfl_xor(pc2[r], o); }
        }
        if (l16 == 0) {
            #pragma unroll
            for (int r = 0; r < 4; ++r) {
                red[64  + (quad * 4 + r) * 4 + wave] = pe[r];
                red[128 + (quad * 4 + r) * 4 + wave] = pc2[r];
            }
        }
        __syncthreads();
        #pragma unroll
        for (int r = 0; r < 4; ++r) {
            const int row16 = quad * 4 + r;
            const float inv = 1.f / (red[64 + row16 * 4] + red[64 + row16 * 4 + 1] +
                                     red[64 + row16 * 4 + 2] + red[64 + row16 * 4 + 3]);
            #pragma unroll
            for (int ci = 0; ci < 2; ++ci) {
                const int bcol = (wave + 4 * ci) * 16 + l16;
                outb[(size_t)(m0 + row16) * 128 + bcol] = f2b(acc[ci][r] * e[ci][r] * inv);
            }
        }
        if (wave == 0 && l16 == 0) {
            #pragma unroll
            for (int r = 0; r < 4; ++r) {
                const int row16 = quad * 4 + r;
                outf[m0 + row16] = 1.f + red[128 + row16 * 4] + red[128 + row16 * 4 + 1] +
                                   red[128 + row16 * 4 + 2] + red[128 + row16 * 4 + 3] + q2[0];
            }
        }
    } else if constexpr (EPI == EPR_HZ) {
        float* ep = (float*)Bsm;
        const float D0 = q0[0];
        if (wave >= 2) {
            #pragma unroll
            for (int c = 0; c < NF; ++c) {
                const int lc = (wave * NF + c) * 16 + l16;
                const float bz = bias[512 + by * 256 + lc - 256];
                #pragma unroll
                for (int r = 0; r < 4; ++r) {
                    const float z = acc[c][r] + bz;
                    ep[(quad * 4 + r) * 256 + lc - 256] = z / (1.f + __expf(-z)) + D0;
                }
            }
        }
        __syncthreads();
        if (wave < 2) {
            #pragma unroll
            for (int c = 0; c < NF; ++c) {
                const int lc = (wave * NF + c) * 16 + l16;
                const float bh = bias[by * 256 + lc];
                #pragma unroll
                for (int r = 0; r < 4; ++r) {
                    const float v = (acc[c][r] + bh) * ep[(quad * 4 + r) * 256 + lc];
                    outb[(size_t)(m0 + quad * 4 + r) * 512 + by * 256 + lc] = f2b(v);
                }
            }
        }
    } else {  // EPR_FINAL
        float fv[NF][4], s[4], q[4];
        #pragma unroll
        for (int r = 0; r < 4; ++r) { s[r] = 0.f; q[r] = 0.f; }
        #pragma unroll
        for (int c = 0; c < NF; ++c) {
            const int col = (wave * NF + c) * 16 + l16;
            #pragma unroll
            for (int r = 0; r < 4; ++r) {
                const size_t idx = (size_t)(m0 + quad * 4 + r) * 256 + col;
                const float g = 1.f / (1.f + __expf(-acc[c][r]));
                const float f = g * q0[idx] + (1.f - g) * q1[idx] + q2[idx];
                fv[c][r] = f; s[r] += f; q[r] += f * f;
            }
        }
        #pragma unroll
        for (int r = 0; r < 4; ++r) {
            #pragma unroll
            for (int o = 1; o < 16; o <<= 1) { s[r] += __shfl_xor(s[r], o); q[r] += __shfl_xor(q[r], o); }
        }
        if (l16 == 0) {
            #pragma unroll
            for (int r = 0; r < 4; ++r) {
                red[(quad * 4 + r) * 8 + wave * 2]     = s[r];
                red[(quad * 4 + r) * 8 + wave * 2 + 1] = q[r];
            }
        }
        __syncthreads();
        #pragma unroll
        for (int r = 0; r < 4; ++r) {
            const int row16 = quad * 4 + r;
            float S = 0.f, Q = 0.f;
            #pragma unroll
            for (int w = 0; w < 4; ++w) { S += red[row16 * 8 + w * 2]; Q += red[row16 * 8 + w * 2 + 1]; }
            const float mean = S * (1.f / 256.f);
            const float rstd = rsqrtf(Q * (1.f / 256.f) - mean * mean + 1e-5f);
            #pragma unroll
            for (int c = 0; c < NF; ++c) {
                const int col = (wave * NF + c) * 16 + l16;
                outf[(size_t)(m0 + row16) * 256 + col] = (fv[c][r] - mean) * rstd * q3[col] + q4[col];
            }
        }
    }
}

// ---------------------------------------------------------------------------
// Fused GAT attention v7: double-buffered software pipeline with manual
// vmcnt barriers. Block: 64 i-rows, js=4 (grid 512 = 2 blocks/CU, all
// resident). 32 chunks of 64 j. Per iter: DMA(k+1) [8 vm] + adj/dA
// prefetch(k+2) [8 vm] + P(k+1)->wsm[(k+1)&1] + barrier(vmcnt 16) +
// MFMA(k) + barrier(lgkm). The vmcnt(16) drains only DMA(k) (one iter in
// flight) — adj HBM latency is hidden by a full chunk of work.
// ---------------------------------------------------------------------------
#define ATTN_PREF(paN, pdN, T)                                                    \
    {                                                                              \
        _Pragma("unroll")                                                          \
        for (int gi = 0; gi < 2; ++gi) {                                           \
            const int g = pc + gi * 4;                                             \
            paN[gi][0] = *(const int4*)(adjp + (T) * 64 + g * 8);                  \
            paN[gi][1] = *(const int4*)(adjp + (T) * 64 + g * 8 + 4);              \
            pdN[gi][0] = *(const float4*)(dAp + (T) * 64 + g * 8);                 \
            pdN[gi][1] = *(const float4*)(dAp + (T) * 64 + g * 8 + 4);             \
        }                                                                          \
    }

#define ATTN_DMA(BUF, T)                                                          \
    {                                                                              \
        _Pragma("unroll")                                                          \
        for (int p = 0; p < 8; ++p) {                                              \
            const int f = wave * 64 + p * 8 + lr;                                  \
            load_lds_16(WhT + (size_t)f * 8192 + jbase + (T) * 64 + ((ls ^ (f & 7)) * 8), \
                        vsm[BUF] + (wave * 64 + p * 8) * 64);                      \
        }                                                                          \
    }

#define ATTN_PCOMP(paC, pdC, BUF)                                                 \
    {                                                                              \
        _Pragma("unroll")                                                          \
        for (int gi = 0; gi < 2; ++gi) {                                           \
            const int g = pc + gi * 4;                                             \
            const int aa[8] = {paC[gi][0].x, paC[gi][0].y, paC[gi][0].z, paC[gi][0].w, \
                               paC[gi][1].x, paC[gi][1].y, paC[gi][1].z, paC[gi][1].w}; \
            const float dd[8] = {pdC[gi][0].x, pdC[gi][0].y, pdC[gi][0].z, pdC[gi][0].w, \
                                 pdC[gi][1].x, pdC[gi][1].y, pdC[gi][1].z, pdC[gi][1].w}; \
            union { ushort us[8]; uint4 v; } pk;                                   \
            _Pragma("unroll")                                                      \
            for (int q = 0; q < 8; ++q) {                                          \
                float e = s_r + dd[q];                                             \
                e = fmaxf(e, 0.2f * e);                                            \
                const float w = aa[q] ? __expf(e) : 0.f;                           \
                lsum += w; pk.us[q] = f2b(w);                                      \
            }                                                                      \
            *(uint4*)(wsm[BUF] + pr * 64 + ((g ^ (pr & 7)) * 8)) = pk.v;           \
        }                                                                          \
    }

#define ATTN_MFMA(BUF)                                                            \
    {                                                                              \
        _Pragma("unroll")                                                          \
        for (int ks = 0; ks < 2; ++ks) {                                           \
            const int sl = ((ks * 4 + quad) ^ (l16 & 7)) * 8;                      \
            short8 a0 = *(const short8*)(wsm[BUF] + (rt * 32 + l16) * 64 + sl);    \
            short8 a1 = *(const short8*)(wsm[BUF] + (rt * 32 + 16 + l16) * 64 + sl); \
            _Pragma("unroll")                                                      \
            for (int c = 0; c < 8; ++c) {                                          \
                short8 bf = *(const short8*)(vsm[BUF] + (ch * 128 + c * 16 + l16) * 64 + sl); \
                acc[0][c] = __builtin_amdgcn_mfma_f32_16x16x32_bf16(a0, bf, acc[0][c], 0, 0, 0); \
                acc[1][c] = __builtin_amdgcn_mfma_f32_16x16x32_bf16(a1, bf, acc[1][c], 0, 0, 0); \
            }                                                                      \
        }                                                                          \
    }

// iter K (even macro-expansion parity): DMA(k+1)->PB, prefetch(k+2)->set[K&1],
// P(k+1) from set[(K+1)&1] -> wsm[PB], barrier, MFMA(k) on MB, barrier.
#define ATTN_ITER(K, MB, PB, paC, pdC, paN, pdN)                                  \
    {                                                                              \
        const int tD = ((K) + 1 < 32) ? (K) + 1 : 31;                              \
        const int tP = ((K) + 2 < 32) ? (K) + 2 : 31;                              \
        ATTN_DMA(PB, tD)                                                           \
        ATTN_PREF(paN, pdN, tP)                                                    \
        if ((K) + 1 < 32) { ATTN_PCOMP(paC, pdC, PB) }                             \
        barrier_vm16();                                                            \
        ATTN_MFMA(MB)                                                              \
        barrier_lgkm();                                                            \
    }

__global__ __launch_bounds__(256, 2) void attn_kernel(
    const int* __restrict__ adj, const float* __restrict__ sA,
    const float* __restrict__ dA, const ushort* __restrict__ WhT,
    float* __restrict__ Upart, float* __restrict__ lpart)
{
    __shared__ ushort vsm[2][256 * 64];   // 64 KB
    __shared__ ushort wsm[2][64 * 64];    // 16 KB

    const int tid  = threadIdx.x;
    const int wave = tid >> 6, lane = tid & 63, quad = lane >> 4, l16 = lane & 15;
    const int lr = lane >> 3, ls = lane & 7;
    const int i0 = blockIdx.x * 64;
    const int js = blockIdx.y;
    const int jbase = js * 2048;
    const int pr = tid >> 2, pc = tid & 3;
    const float s_r = sA[i0 + pr];
    const int* adjp = adj + (size_t)(i0 + pr) * 8192 + jbase;
    const float* dAp = dA + jbase;
    const int rt = wave & 1, ch = wave >> 1;

    f32x4 zero = {0.f, 0.f, 0.f, 0.f};
    f32x4 acc[2][8] = {{zero, zero, zero, zero, zero, zero, zero, zero},
                       {zero, zero, zero, zero, zero, zero, zero, zero}};
    float lsum = 0.f;

    int4   pa0[2][2], pa1[2][2];
    float4 pd0[2][2], pd1[2][2];

    // pre-loop: chunk0->set0 [8 vm], DMA(0)->vsm[0] [8 vm], chunk1->set1 [8 vm],
    // P(0)->wsm[0] (compiler auto-waits the set0 loads; one cold-latency hit).
    ATTN_PREF(pa0, pd0, 0)
    ATTN_DMA(0, 0)
    ATTN_PREF(pa1, pd1, 1)
    ATTN_PCOMP(pa0, pd0, 0)

    #pragma unroll 1
    for (int k = 0; k < 32; k += 2) {
        ATTN_ITER(k,     0, 1, pa1, pd1, pa0, pd0)
        ATTN_ITER(k + 1, 1, 0, pa0, pd0, pa1, pd1)
    }

    lsum += __shfl_down(lsum, 1);
    lsum += __shfl_down(lsum, 2);
    if (pc == 0) lpart[(size_t)js * 8192 + i0 + pr] = lsum;

    #pragma unroll
    for (int it = 0; it < 2; ++it) {
        #pragma unroll
        for (int c = 0; c < 8; ++c) {
            const int col = ch * 128 + c * 16 + l16;
            #pragma unroll
            for (int r = 0; r < 4; ++r) {
                const int row = i0 + rt * 32 + it * 16 + quad * 4 + r;
                Upart[((size_t)js * 8192 + row) * 256 + col] = acc[it][c][r];
            }
        }
    }
}

// ---------------------------------------------------------------------------
// post_attn: blocks [0,2048) combine; [2048,2560) fe1+LN+silu; [2560,3072) bcdt
// ---------------------------------------------------------------------------
__global__ __launch_bounds__(256) void post_attn_kernel(
    const float* __restrict__ Upart, const float* __restrict__ lpart,
    float* __restrict__ hattn, ushort* __restrict__ comb,
    const ushort* __restrict__ Whbf,
    const ushort* __restrict__ fe1T, const float* __restrict__ fe1_b,
    const float* __restrict__ fe_ln_g, const float* __restrict__ fe_ln_b,
    ushort* __restrict__ tact,
    const ushort* __restrict__ bcdtT, const float* __restrict__ b_bcdt,
    const float* __restrict__ Avec, const float* __restrict__ cpw,
    const float* __restrict__ cpb,
    ushort* __restrict__ SB, float* __restrict__ cscl)
{
    __shared__ ushort Asm[16 * 64];
    __shared__ ushort Bsm[512 * 64];
    __shared__ float red[192];
    const int b = blockIdx.x;

    if (b < 2048) {
        const int row = b * 4 + (threadIdx.x >> 6);
        const int lane = threadIdx.x & 63;
        float l = 0.f;
        #pragma unroll
        for (int js = 0; js < 4; ++js) l += lpart[(size_t)js * 8192 + row];
        const float inv = 1.f / l;
        float4 u = {0.f, 0.f, 0.f, 0.f};
        #pragma unroll
        for (int js = 0; js < 4; ++js) {
            const float4 t = *(const float4*)&Upart[((size_t)js * 8192 + row) * 256 + lane * 4];
            u.x += t.x; u.y += t.y; u.z += t.z; u.w += t.w;
        }
        u.x *= inv; u.y *= inv; u.z *= inv; u.w *= inv;
        *(float4*)&hattn[(size_t)row * 256 + lane * 4] = u;
        union { ushort us[4]; uint2 v; } pk;
        pk.us[0] = f2b(u.x); pk.us[1] = f2b(u.y); pk.us[2] = f2b(u.z); pk.us[3] = f2b(u.w);
        *(uint2*)&comb[(size_t)row * 512 + lane * 4] = pk.v;
    } else if (b < 2560) {
        gemm_row_dev<256, 512, EPR_LNSILU>(Whbf, fe1T, fe1_b, nullptr, tact,
            fe_ln_g, fe_ln_b, nullptr, nullptr, nullptr, b - 2048, 0, Asm, Bsm, red);
    } else {
        gemm_row_dev<256, 384, EPR_BCDT>(Whbf, bcdtT, b_bcdt, cscl, SB,
            Avec, cpw, cpb, nullptr, nullptr, b - 2560, 0, Asm, Bsm, red);
    }
}

__global__ __launch_bounds__(256) void gemm_fe2_sb_kernel(
    const ushort* __restrict__ tact, const ushort* __restrict__ fe2T,
    const float* __restrict__ fe2_b, float* __restrict__ henh,
    const ushort* __restrict__ SB, const ushort* __restrict__ abpT,
    const float* __restrict__ abp_b, ushort* __restrict__ hsbf,
    const float* __restrict__ Wh)
{
    __shared__ ushort Asm[64 * 64];
    __shared__ ushort Bsm[64 * 64];
    const int b = blockIdx.x;
    if (b < 512)
        gemm_k_dev<512, EPI_F32>(tact, fe2T, fe2_b, 256, henh, nullptr, 0, 0,
                                 nullptr, b & 127, b >> 7, Asm, Bsm);
    else
        gemm_k_dev<128, EPI_MUL_BF16>(SB, abpT, abp_b, 256, nullptr, hsbf, 256, 0,
                                      Wh, (b - 512) & 127, (b - 512) >> 7, Asm, Bsm);
}

__global__ __launch_bounds__(256) void gemm_hz_kernel(
    const ushort* __restrict__ hsbf, const ushort* __restrict__ hzT,
    const float* __restrict__ b_hz, ushort* __restrict__ vbf,
    const float* __restrict__ Dvec)
{
    __shared__ ushort Asm[16 * 64];
    __shared__ ushort Bsm[512 * 64];
    __shared__ float red[192];
    gemm_row_dev<256, 512, EPR_HZ>(hsbf, hzT, b_hz, nullptr, vbf, Dvec,
        nullptr, nullptr, nullptr, nullptr, blockIdx.x, blockIdx.y, Asm, Bsm, red);
}

__global__ __launch_bounds__(256) void gemm_out_kernel(
    const ushort* __restrict__ vbf, const ushort* __restrict__ outT,
    const float* __restrict__ out_b, float* __restrict__ hs2,
    ushort* __restrict__ comb, const float* __restrict__ cscl)
{
    __shared__ ushort Asm[64 * 64];
    __shared__ ushort Bsm[64 * 64];
    gemm_k_dev<512, EPI_SCALE_FB>(vbf, outT, out_b, 256, hs2, comb, 512, 256,
                                  cscl, blockIdx.x, blockIdx.y, Asm, Bsm);
}

__global__ __launch_bounds__(256) void gemm_g1_kernel(
    const ushort* __restrict__ comb, const ushort* __restrict__ g1T,
    const float* __restrict__ g1_b, ushort* __restrict__ tact,
    const float* __restrict__ g_ln_g, const float* __restrict__ g_ln_b)
{
    __shared__ ushort Asm[16 * 64];
    __shared__ ushort Bsm[512 * 64];
    __shared__ float red[192];
    gemm_row_dev<512, 512, EPR_LNSILU>(comb, g1T, g1_b, nullptr, tact,
        g_ln_g, g_ln_b, nullptr, nullptr, nullptr, blockIdx.x, 0, Asm, Bsm, red);
}

__global__ __launch_bounds__(256) void gemm_final_kernel(
    const ushort* __restrict__ tact, const ushort* __restrict__ g2T,
    const float* __restrict__ g2_b, float* __restrict__ outp,
    const float* __restrict__ hattn, const float* __restrict__ hs2,
    const float* __restrict__ henh, const float* __restrict__ ln_g,
    const float* __restrict__ ln_b)
{
    __shared__ ushort Asm[16 * 64];
    __shared__ ushort Bsm[256 * 64];
    __shared__ float red[192];
    gemm_row_dev<512, 256, EPR_FINAL>(tact, g2T, g2_b, outp, nullptr,
        hattn, hs2, henh, ln_g, ln_b, blockIdx.x, 0, Asm, Bsm, red);
}

// ---------------------------------------------------------------------------
// Descriptor-driven transpose/cast mega-kernel (+ hz column permutation)
// ---------------------------------------------------------------------------
struct TJob { const float* in; ushort* out; int R, C, off, perm; };
struct TArgs { TJob j[10]; };

DEVINL int hzperm(int j) {
    return (j < 512) ? ((j >> 8) << 9) + (j & 255)
                     : (((j - 512) >> 8) << 9) + 256 + ((j - 512) & 255);
}

__global__ __launch_bounds__(256) void multi_transpose_kernel(TArgs a)
{
    __shared__ float tile[32][33];
    const int b = blockIdx.x;
    int ji = 0;
    #pragma unroll
    for (int k = 1; k < 10; ++k) if (b >= a.j[k].off) ji = k;
    const TJob J = a.j[ji];
    const int t = b - J.off;

    if (J.R == 0) {
        const int base = t * 1024 + threadIdx.x;
        #pragma unroll
        for (int k = 0; k < 4; ++k)
            J.out[base + k * 256] = f2b(J.in[base + k * 256]);
        return;
    }
    const int CB = J.C >> 5;
    const int bx = t % CB, by = t / CB;
    const int tx = threadIdx.x & 31, ty = threadIdx.x >> 5;
    const int c0 = bx * 32, r0 = by * 32;
    #pragma unroll
    for (int i = ty; i < 32; i += 8)
        tile[i][tx] = J.in[(size_t)(r0 + i) * J.C + (c0 + tx)];
    __syncthreads();
    #pragma unroll
    for (int i = ty; i < 32; i += 8) {
        int orow = c0 + i;
        if (J.perm) orow = hzperm(orow);
        J.out[(size_t)orow * J.R + (r0 + tx)] = f2b(tile[tx][i]);
    }
}

// ---------------------------------------------------------------------------
extern "C" void kernel_launch(void* const* d_in, const int* in_sizes, int n_in,
                              void* d_out, int out_size, void* d_ws, size_t ws_size,
                              hipStream_t stream)
{
    const float* h      = (const float*)d_in[0];
    const int*   adj    = (const int*)  d_in[1];
    const float* W      = (const float*)d_in[2];
    const float* a_src  = (const float*)d_in[3];
    const float* a_dst  = (const float*)d_in[4];
    const float* W_bcdt = (const float*)d_in[5];
    const float* b_bcdt = (const float*)d_in[6];
    const float* abp_w  = (const float*)d_in[7];
    const float* abp_b  = (const float*)d_in[8];
    const float* cp_w   = (const float*)d_in[9];
    const float* cp_b   = (const float*)d_in[10];
    const float* W_hz   = (const float*)d_in[11];
    const float* b_hz   = (const float*)d_in[12];
    const float* out_w  = (const float*)d_in[13];
    const float* out_b  = (const float*)d_in[14];
    const float* fe1_w  = (const float*)d_in[15];
    const float* fe1_b  = (const float*)d_in[16];
    const float* fe_ln_g= (const float*)d_in[17];
    const float* fe_ln_b= (const float*)d_in[18];
    const float* fe2_w  = (const float*)d_in[19];
    const float* fe2_b  = (const float*)d_in[20];
    const float* Avec   = (const float*)d_in[21];
    const float* Dvec   = (const float*)d_in[22];
    const float* g1_w   = (const float*)d_in[23];
    const float* g1_b   = (const float*)d_in[24];
    const float* g_ln_g = (const float*)d_in[25];
    const float* g_ln_b = (const float*)d_in[26];
    const float* g2_w   = (const float*)d_in[27];
    const float* g2_b   = (const float*)d_in[28];
    const float* ln_g   = (const float*)d_in[29];
    const float* ln_b   = (const float*)d_in[30];
    float* outp = (float*)d_out;

    char* p = (char*)d_ws;
    size_t off = 0;
    auto take = [&](size_t nbytes) -> void* {
        void* r = p + off;
        off += (nbytes + 255) & ~(size_t)255;
        return r;
    };
    ushort* wT    = (ushort*)take(256 * 256 * 2);
    ushort* fe1T  = (ushort*)take(512 * 256 * 2);
    ushort* fe2T  = (ushort*)take(256 * 512 * 2);
    ushort* bcdtT = (ushort*)take(384 * 256 * 2);
    ushort* hzT   = (ushort*)take(1024 * 256 * 2);
    ushort* outT  = (ushort*)take(256 * 512 * 2);
    ushort* g1T   = (ushort*)take(512 * 512 * 2);
    ushort* g2T   = (ushort*)take(256 * 512 * 2);
    ushort* abpT  = (ushort*)take(256 * 128 * 2);
    ushort* hbf   = (ushort*)take((size_t)8192 * 256 * 2);
    float*  Wh    = (float*) take((size_t)8192 * 256 * 4);
    ushort* Whbf  = (ushort*)take((size_t)8192 * 256 * 2);
    ushort* WhT   = (ushort*)take((size_t)8192 * 256 * 2);
    float*  sbuf  = (float*) take(8192 * 4);
    float*  dbuf  = (float*) take(8192 * 4);
    float*  cscl  = (float*) take(8192 * 4);
    float*  hattn = (float*) take((size_t)8192 * 256 * 4);
    float*  henh  = (float*) take((size_t)8192 * 256 * 4);
    float*  lpart = (float*) take(4 * 8192 * 4);
    ushort* SB    = (ushort*)take((size_t)8192 * 128 * 2);
    ushort* hsbf  = (ushort*)take((size_t)8192 * 256 * 2);
    ushort* vbf   = (ushort*)take((size_t)8192 * 512 * 2);
    float*  hs2   = (float*) take((size_t)8192 * 256 * 4);
    ushort* comb  = (ushort*)take((size_t)8192 * 512 * 2);
    ushort* tact  = (ushort*)take((size_t)8192 * 512 * 2);
    float*  Upart = (float*) take((size_t)4 * 8192 * 256 * 4);

    (void)in_sizes; (void)n_in; (void)out_size; (void)ws_size;

    hipMemsetAsync(sbuf, 0, 2 * 8192 * sizeof(float), stream);

    // 1) all weight transposes + h cast
    {
        TArgs ta; int boff = 0;
        auto addT = [&](int i, const float* in, ushort* out, int R, int C, int perm) {
            ta.j[i] = TJob{in, out, R, C, boff, perm};
            boff += (R / 32) * (C / 32);
        };
        addT(0, W,      wT,    256, 256,  0);
        addT(1, fe1_w,  fe1T,  256, 512,  0);
        addT(2, fe2_w,  fe2T,  512, 256,  0);
        addT(3, W_bcdt, bcdtT, 256, 384,  0);
        addT(4, abp_w,  abpT,  128, 256,  0);
        addT(5, W_hz,   hzT,   256, 1024, 1);
        addT(6, out_w,  outT,  512, 256,  0);
        addT(7, g1_w,   g1T,   512, 512,  0);
        addT(8, g2_w,   g2T,   512, 256,  0);
        ta.j[9] = TJob{h, hbf, 0, 8192 * 256, boff, 0};
        boff += (8192 * 256) / 1024;
        multi_transpose_kernel<<<boff, 256, 0, stream>>>(ta);
    }

    // 2) Wh gemm (Wh f32 + Whbf + WhT + s/d dots)
    gemm_wh_kernel<<<dim3(128, 4), 256, 0, stream>>>(
        hbf, wT, a_src, a_dst, Wh, Whbf, WhT, sbuf, dbuf);

    // 3) attention (software-pipelined, manual vmcnt barriers, js=4)
    attn_kernel<<<dim3(128, 4), 256, 0, stream>>>(adj, sbuf, dbuf, WhT, Upart, lpart);

    // 4) combine + fe1(+LN+silu) + bcdt(+softmax+cscale)
    post_attn_kernel<<<3072, 256, 0, stream>>>(
        Upart, lpart, hattn, comb, Whbf,
        fe1T, fe1_b, fe_ln_g, fe_ln_b, tact,
        bcdtT, b_bcdt, Avec, cp_w, cp_b, SB, cscl);

    // 5) fe2 + SB gemm
    gemm_fe2_sb_kernel<<<1024, 256, 0, stream>>>(
        tact, fe2T, fe2_b, henh, SB, abpT, abp_b, hsbf, Wh);

    // 6) hz (+ h*(silu(z)+D))
    gemm_hz_kernel<<<dim3(512, 2), 256, 0, stream>>>(hsbf, hzT, b_hz, vbf, Dvec);

    // 7) out gemm (*cscale)
    gemm_out_kernel<<<dim3(128, 4), 256, 0, stream>>>(vbf, outT, out_b, hs2, comb, cscl);

    // 8) g1 (+LN+silu)
    gemm_g1_kernel<<<512, 256, 0, stream>>>(comb, g1T, g1_b, tact, g_ln_g, g_ln_b);

    // 9) g2 + sigmoid + gated fuse + final LN
    gemm_final_kernel<<<512, 256, 0, stream>>>(
        tact, g2T, g2_b, outp, hattn, hs2, henh, ln_g, ln_b);
}